// Round 13
// baseline (319.933 us; speedup 1.0000x reference)
//
#include <hip/hip_runtime.h>
#include <stdint.h>

#define M_DIM 16384
#define N_DIM 4096
#define K_DIM 512

typedef int v8i __attribute__((ext_vector_type(8)));
typedef float f32x16 __attribute__((ext_vector_type(16)));
typedef float f32x4v __attribute__((ext_vector_type(4)));

typedef __attribute__((address_space(3))) uint32_t lds_u32_t;
typedef const __attribute__((address_space(1))) uint32_t glob_u32_t;

__device__ __forceinline__ void gload16(const void* g, void* l) {
    __builtin_amdgcn_global_load_lds((glob_u32_t*)g, (lds_u32_t*)l, 16, 0, 0);
}

// one wave per row: fp32 row -> fp8 e4m3 + fp32 sum of squares.
// A (X) rows are written FRAGMENT-MAJOR:
//   Apack[(P*8+ks)*2048 + h*1024 + r*32 + b] = A[32P + r][64ks + 32h + b]
// B (C) rows are written natural row-major (k contiguous).
__global__ __launch_bounds__(256)
void convert_norm_kernel(const float* __restrict__ X, const float* __restrict__ C,
                         uint8_t* __restrict__ Apack, uint8_t* __restrict__ Bf8,
                         float* __restrict__ xsq, float* __restrict__ csq) {
    const int wave = threadIdx.x >> 6;
    const int lane = threadIdx.x & 63;
    const int row = blockIdx.x * 4 + wave;

    const float* src;
    uint8_t* dst;
    float* nrm;
    int r;
    size_t off;
    if (row < M_DIM) {
        src = X; dst = Apack; nrm = xsq; r = row;
        off = (size_t)((r >> 5) * 8 + (lane >> 3)) * 2048
            + ((lane >> 2) & 1) * 1024 + (r & 31) * 32 + (lane & 3) * 8;
    } else {
        src = C; dst = Bf8; nrm = csq; r = row - M_DIM;
        off = (size_t)r * K_DIM + lane * 8;
    }

    const float4* p = (const float4*)(src + (size_t)r * K_DIM) + lane * 2;
    float4 a = p[0], b = p[1];
    uint32_t lo = 0, hi = 0;
    lo = __builtin_amdgcn_cvt_pk_fp8_f32(a.x, a.y, lo, false);
    lo = __builtin_amdgcn_cvt_pk_fp8_f32(a.z, a.w, lo, true);
    hi = __builtin_amdgcn_cvt_pk_fp8_f32(b.x, b.y, hi, false);
    hi = __builtin_amdgcn_cvt_pk_fp8_f32(b.z, b.w, hi, true);
    *(uint2*)(dst + off) = make_uint2(lo, hi);

    float s = a.x*a.x + a.y*a.y + a.z*a.z + a.w*a.w
            + b.x*b.x + b.y*b.y + b.z*b.z + b.w*b.w;
    #pragma unroll
    for (int o2 = 32; o2 > 0; o2 >>= 1) s += __shfl_down(s, o2, 64);
    if (lane == 0) nrm[r] = s;
}

// Block 128x128, 4 waves each 32x128 (1x4 of mfma_scale 32x32x64 fp8, acc=64 VGPR).
// vs round-9 champion: BK=256 (Bs 32 KB, still 4 blocks/CU at 128 KB LDS) ->
// THREE barriers per block instead of seven; A loads software-pipelined depth-1.
// B LDS: row p (256 B = 16 chunks) <-> global col bn + 4*(p&31) + (p>>5);
// 16B-chunk c of row p at slot (c+p)&15 -> read slot (4*ksl+2h + r31)&15,
// j-independent. Stage side: lane lv covers row q=4w+(lv>>4) (+16 per round),
// slot s=lv&15, source chunk (s-q)&15 — R- and kk-independent.
// k-map identity: A packed (ks,h) holds global chunks {4ks+2h, +1}; B reads
// local chunks {4ksl+2h, +1} of kk-half kk -> global {4(4kk+ksl)+2h, +1} ✓.
__global__ __launch_bounds__(256, 4)
void rbf_mfma_kernel(const uint8_t* __restrict__ Apack, const uint8_t* __restrict__ B8,
                     const float* __restrict__ xsq, const float* __restrict__ csq,
                     float* __restrict__ out) {
    __shared__ uint8_t Bs[128 * 256];   // 32 KB

    const int tid = threadIdx.x;
    const int lv  = tid & 63;
    const int w   = tid >> 6;
    const int h   = lv >> 5;
    const int r31 = lv & 31;

    const int bn = (blockIdx.x & 31) * 128;   // bn fastest -> A-slab L2 reuse
    const int bm = (blockIdx.x >> 5) * 128;

    // ---- B staging map (wave-uniform LDS dest; per-lane global addr) ----
    const int q  = 4 * w + (lv >> 4);       // base row (rows advance +16/round)
    const int s  = lv & 15;                 // dest slot (HW: lane*16)
    const int cb = (s - q) & 15;            // swizzled source chunk
    const uint8_t* gB0 = B8 + (size_t)(bn + 4 * q) * K_DIM + cb * 16;
    uint8_t* BsW = Bs + w * 1024;

    // ---- A fragment base (wave-private 32-row slab, packed) ----
    const uint8_t* aB = Apack + (size_t)((bm >> 5) + w) * 16384 + h * 1024 + r31 * 32;

    const uint8_t* bRow = Bs + r31 * 256;

    f32x16 acc[4] = {};   // 64 VGPRs

    #pragma unroll
    for (int kk = 0; kk < 2; ++kk) {
        // stage 32 KB of B: 8 rounds; round R covers rows 16R+q, col bump per R
        #pragma unroll
        for (int R = 0; R < 8; ++R) {
            const uint8_t* g = gB0 + (size_t)((R & 1) * 64) * K_DIM
                             + (R >> 1) * K_DIM + kk * 256;
            gload16(g, BsW + R * 4096);
        }
        // A pipeline head for this kk
        uint4 p0 = *(const uint4*)(aB + (4 * kk) * 2048);
        uint4 p1 = *(const uint4*)(aB + (4 * kk) * 2048 + 16);
        __syncthreads();

        #pragma unroll
        for (int ksl = 0; ksl < 4; ++ksl) {
            uint4 n0, n1;
            if (ksl < 3) {
                n0 = *(const uint4*)(aB + (4 * kk + ksl + 1) * 2048);
                n1 = *(const uint4*)(aB + (4 * kk + ksl + 1) * 2048 + 16);
            }
            v8i av = (v8i){(int)p0.x, (int)p0.y, (int)p0.z, (int)p0.w,
                           (int)p1.x, (int)p1.y, (int)p1.z, (int)p1.w};
            const int c0 = 4 * ksl + 2 * h;
            const int s0 = ((c0 + 0 + r31) & 15) * 16;
            const int s1 = ((c0 + 1 + r31) & 15) * 16;
            #pragma unroll
            for (int j = 0; j < 4; ++j) {
                uint4 lo = *(const uint4*)(bRow + j * 8192 + s0);
                uint4 hi = *(const uint4*)(bRow + j * 8192 + s1);
                v8i bv = (v8i){(int)lo.x, (int)lo.y, (int)lo.z, (int)lo.w,
                               (int)hi.x, (int)hi.y, (int)hi.z, (int)hi.w};
                acc[j] = __builtin_amdgcn_mfma_scale_f32_32x32x64_f8f6f4(
                    av, bv, acc[j],
                    0 /*fp8*/, 0 /*fp8*/,
                    0, 0x7F7F7F7Fu, 0, 0x7F7F7F7Fu);
            }
            p0 = n0; p1 = n1;
        }
        if (kk == 0) __syncthreads();
    }

    // ---- epilogue: out = exp(-(xsq - 2*cross + csq)), NT float4 stores ----
    // C/D 32x32: col = lane&31 -> global col bn + 4*r31 + j (col interleave);
    // row = (reg&3) + 8*(reg>>2) + 4h
    const float4 cs4 = *(const float4*)(csq + bn + 4 * r31);
    const int mbase = bm + 32 * w + 4 * h;

    #pragma unroll
    for (int g = 0; g < 4; ++g) {
        const float4 xs4 = *(const float4*)(xsq + mbase + 8 * g);
        #pragma unroll
        for (int rr = 0; rr < 4; ++rr) {
            const int reg = g * 4 + rr;
            const float xs = (rr == 0) ? xs4.x : (rr == 1) ? xs4.y
                           : (rr == 2) ? xs4.z : xs4.w;
            const int gm = mbase + 8 * g + rr;
            f32x4v o;
            o.x = __expf(-(xs - 2.0f * acc[0][reg] + cs4.x));
            o.y = __expf(-(xs - 2.0f * acc[1][reg] + cs4.y));
            o.z = __expf(-(xs - 2.0f * acc[2][reg] + cs4.z));
            o.w = __expf(-(xs - 2.0f * acc[3][reg] + cs4.w));
            __builtin_nontemporal_store(
                o, (f32x4v*)(out + (size_t)gm * N_DIM + bn + 4 * r31));
        }
    }
}

extern "C" void kernel_launch(void* const* d_in, const int* in_sizes, int n_in,
                              void* d_out, int out_size, void* d_ws, size_t ws_size,
                              hipStream_t stream) {
    const float* X = (const float*)d_in[0];
    const float* C = (const float*)d_in[1];
    float* out = (float*)d_out;

    uint8_t* Apack = (uint8_t*)d_ws;                          // 8 MB
    uint8_t* Bf8 = Apack + (size_t)M_DIM * K_DIM;             // 2 MB
    float* xsq = (float*)(Bf8 + (size_t)N_DIM * K_DIM);       // 64 KB
    float* csq = xsq + M_DIM;                                 // 16 KB

    convert_norm_kernel<<<(M_DIM + N_DIM) / 4, 256, 0, stream>>>(X, C, Apack, Bf8, xsq, csq);
    rbf_mfma_kernel<<<(M_DIM / 128) * (N_DIM / 128), 256, 0, stream>>>(Apack, Bf8, xsq, csq, out);
}

// Round 14
// 303.844 us; speedup vs baseline: 1.0530x; 1.0530x over previous
//
#include <hip/hip_runtime.h>
#include <stdint.h>

#define M_DIM 16384
#define N_DIM 4096
#define K_DIM 512

typedef int v8i __attribute__((ext_vector_type(8)));
typedef float f32x16 __attribute__((ext_vector_type(16)));
typedef float f32x4v __attribute__((ext_vector_type(4)));

typedef __attribute__((address_space(3))) uint32_t lds_u32_t;
typedef const __attribute__((address_space(1))) uint32_t glob_u32_t;

__device__ __forceinline__ void gload16(const void* g, void* l) {
    __builtin_amdgcn_global_load_lds((glob_u32_t*)g, (lds_u32_t*)l, 16, 0, 0);
}

// one wave per row: fp32 row -> fp8 e4m3 + fp32 sum of squares.
// A (X) rows are written FRAGMENT-MAJOR:
//   Apack[(P*8+ks)*2048 + h*1024 + r*32 + b] = A[32P + r][64ks + 32h + b]
// B (C) rows are written natural row-major (k contiguous).
__global__ __launch_bounds__(256)
void convert_norm_kernel(const float* __restrict__ X, const float* __restrict__ C,
                         uint8_t* __restrict__ Apack, uint8_t* __restrict__ Bf8,
                         float* __restrict__ xsq, float* __restrict__ csq) {
    const int wave = threadIdx.x >> 6;
    const int lane = threadIdx.x & 63;
    const int row = blockIdx.x * 4 + wave;

    const float* src;
    uint8_t* dst;
    float* nrm;
    int r;
    size_t off;
    if (row < M_DIM) {
        src = X; dst = Apack; nrm = xsq; r = row;
        off = (size_t)((r >> 5) * 8 + (lane >> 3)) * 2048
            + ((lane >> 2) & 1) * 1024 + (r & 31) * 32 + (lane & 3) * 8;
    } else {
        src = C; dst = Bf8; nrm = csq; r = row - M_DIM;
        off = (size_t)r * K_DIM + lane * 8;
    }

    const float4* p = (const float4*)(src + (size_t)r * K_DIM) + lane * 2;
    float4 a = p[0], b = p[1];
    uint32_t lo = 0, hi = 0;
    lo = __builtin_amdgcn_cvt_pk_fp8_f32(a.x, a.y, lo, false);
    lo = __builtin_amdgcn_cvt_pk_fp8_f32(a.z, a.w, lo, true);
    hi = __builtin_amdgcn_cvt_pk_fp8_f32(b.x, b.y, hi, false);
    hi = __builtin_amdgcn_cvt_pk_fp8_f32(b.z, b.w, hi, true);
    *(uint2*)(dst + off) = make_uint2(lo, hi);

    float s = a.x*a.x + a.y*a.y + a.z*a.z + a.w*a.w
            + b.x*b.x + b.y*b.y + b.z*b.z + b.w*b.w;
    #pragma unroll
    for (int o2 = 32; o2 > 0; o2 >>= 1) s += __shfl_down(s, o2, 64);
    if (lane == 0) nrm[r] = s;
}

// ROUND-9 CHAMPION (restored). Block 128x128, 4 waves each 32x128 (1x4 of
// mfma_scale 32x32x64 fp8, acc=64 VGPR). B-ONLY LDS (16 KB, 4 blocks/CU);
// A direct from fragment-packed global (coalesced dwordx4, LLC-hot; issued
// before __syncthreads so the barrier's structural vmcnt(0) drain hides their
// latency). Epilogue: col-interleaved NT float4 stores.
// B LDS: row p (128 B) <-> global col bn + 4*(p&31) + (p>>5) (col interleave);
// chunk c of row p at slot (c+p)&7 -> conflict-free ds_read_b128.
// k-map identity: A packed (ks=2kk+ksl, h) holds chunks {kk*8 + ksl*4+2h, +1};
// B reads chunks {kk*8 + c0, +1}, c0 = ksl*4+2h -> identical, lane-row-indep.
__global__ __launch_bounds__(256, 4)
void rbf_mfma_kernel(const uint8_t* __restrict__ Apack, const uint8_t* __restrict__ B8,
                     const float* __restrict__ xsq, const float* __restrict__ csq,
                     float* __restrict__ out) {
    __shared__ uint8_t Bs[128 * 128];   // 16 KB

    const int tid = threadIdx.x;
    const int lv  = tid & 63;
    const int w   = tid >> 6;
    const int h   = lv >> 5;
    const int r31 = lv & 31;

    const int bn = (blockIdx.x & 31) * 128;   // bn fastest -> A-slab L2 reuse
    const int bm = (blockIdx.x >> 5) * 128;

    // ---- B staging map ----
    const int tr = tid >> 3;            // 0..31
    const int tc = tid & 7;
    const int cc = (tc - tr) & 7;
    const uint8_t* gB = B8 + (size_t)(bn + 4 * tr) * K_DIM + cc * 16;
    uint8_t* BsW = Bs + w * 1024;

    // ---- A fragment base (wave-private 32-row slab, packed) ----
    const uint8_t* aB = Apack + (size_t)((bm >> 5) + w) * 16384 + h * 1024 + r31 * 32;

    const uint8_t* bRow = Bs + r31 * 128;

    f32x16 acc[4] = {};   // 64 VGPRs

    for (int kk = 0; kk < 4; ++kk) {
        const int koff = kk * 128;
        #pragma unroll
        for (int R = 0; R < 4; ++R)
            gload16(gB + koff + (size_t)R * K_DIM, BsW + R * 4096);

        // A loads for this kk — issued before the barrier; its vmcnt(0) drain
        // (structural) covers their L2 latency at zero extra cost.
        uint4 a0[2], a1[2];
        #pragma unroll
        for (int ksl = 0; ksl < 2; ++ksl) {
            const uint8_t* ap = aB + (2 * kk + ksl) * 2048;
            a0[ksl] = *(const uint4*)(ap);
            a1[ksl] = *(const uint4*)(ap + 16);
        }
        __syncthreads();

        #pragma unroll
        for (int ksl = 0; ksl < 2; ++ksl) {
            v8i av = (v8i){(int)a0[ksl].x, (int)a0[ksl].y, (int)a0[ksl].z, (int)a0[ksl].w,
                           (int)a1[ksl].x, (int)a1[ksl].y, (int)a1[ksl].z, (int)a1[ksl].w};
            const int c0 = ksl * 4 + 2 * h;
            const int s0 = ((c0 + 0 + r31) & 7) * 16;
            const int s1 = ((c0 + 1 + r31) & 7) * 16;
            #pragma unroll
            for (int j = 0; j < 4; ++j) {
                uint4 lo = *(const uint4*)(bRow + j * 4096 + s0);
                uint4 hi = *(const uint4*)(bRow + j * 4096 + s1);
                v8i bv = (v8i){(int)lo.x, (int)lo.y, (int)lo.z, (int)lo.w,
                               (int)hi.x, (int)hi.y, (int)hi.z, (int)hi.w};
                acc[j] = __builtin_amdgcn_mfma_scale_f32_32x32x64_f8f6f4(
                    av, bv, acc[j],
                    0 /*fp8*/, 0 /*fp8*/,
                    0, 0x7F7F7F7Fu, 0, 0x7F7F7F7Fu);
            }
        }
        if (kk < 3) __syncthreads();
    }

    // ---- epilogue: out = exp(-(xsq - 2*cross + csq)), NT float4 stores ----
    // C/D 32x32: col = lane&31 -> global col bn + 4*r31 + j (col interleave);
    // row = (reg&3) + 8*(reg>>2) + 4h
    const float4 cs4 = *(const float4*)(csq + bn + 4 * r31);
    const int mbase = bm + 32 * w + 4 * h;

    #pragma unroll
    for (int g = 0; g < 4; ++g) {
        const float4 xs4 = *(const float4*)(xsq + mbase + 8 * g);
        #pragma unroll
        for (int rr = 0; rr < 4; ++rr) {
            const int reg = g * 4 + rr;
            const float xs = (rr == 0) ? xs4.x : (rr == 1) ? xs4.y
                           : (rr == 2) ? xs4.z : xs4.w;
            const int gm = mbase + 8 * g + rr;
            f32x4v o;
            o.x = __expf(-(xs - 2.0f * acc[0][reg] + cs4.x));
            o.y = __expf(-(xs - 2.0f * acc[1][reg] + cs4.y));
            o.z = __expf(-(xs - 2.0f * acc[2][reg] + cs4.z));
            o.w = __expf(-(xs - 2.0f * acc[3][reg] + cs4.w));
            __builtin_nontemporal_store(
                o, (f32x4v*)(out + (size_t)gm * N_DIM + bn + 4 * r31));
        }
    }
}

extern "C" void kernel_launch(void* const* d_in, const int* in_sizes, int n_in,
                              void* d_out, int out_size, void* d_ws, size_t ws_size,
                              hipStream_t stream) {
    const float* X = (const float*)d_in[0];
    const float* C = (const float*)d_in[1];
    float* out = (float*)d_out;

    uint8_t* Apack = (uint8_t*)d_ws;                          // 8 MB
    uint8_t* Bf8 = Apack + (size_t)M_DIM * K_DIM;             // 2 MB
    float* xsq = (float*)(Bf8 + (size_t)N_DIM * K_DIM);       // 64 KB
    float* csq = xsq + M_DIM;                                 // 16 KB

    convert_norm_kernel<<<(M_DIM + N_DIM) / 4, 256, 0, stream>>>(X, C, Apack, Bf8, xsq, csq);
    rbf_mfma_kernel<<<(M_DIM / 128) * (N_DIM / 128), 256, 0, stream>>>(Apack, Bf8, xsq, csq, out);
}